// Round 1
// baseline (350.383 us; speedup 1.0000x reference)
//
#include <hip/hip_runtime.h>

// ---------------------------------------------------------------------------
// Attention_4956392259713 — round 8: deep-pipelined 256^2 GEMM core (T3+T4+T5).
// qkv = x@W^T+b; S = q@k^T (unscaled); P = softmax(S); out = P@v
//
// Round-7 counters: K2 74us = 696 TF, MfmaUtil 28%, HBM 18%, bank-conflicts
// ~1cyc/ds_read (negligible). Limiter is the m97-style 2-barrier loop whose
// __syncthreads() drains vmcnt(0) every K-step (~900 TF structural cap).
// Round-8 core: BM=BN=256, BK=32, 512 thr = 8 waves (2Mx4N), per-wave C =
// 128x64 (acc 8x4 f32x4 = 128 VGPR). LDS = 4-deep circular x (A,B) x 16KB
// = 128KB, 1 block/CU. Two phases per K-tile:
//   phase: ds_read frags (8 or 4 x b128) ; issue 2 global_load_lds (tile t+3
//          into the slot freed at iter t-1) ; s_barrier ; lgkmcnt(0) ;
//          setprio(1) ; 16 MFMA ; setprio(0) ; [vmcnt(8) counted] ; s_barrier
// vmcnt(8) keeps 2 full K-tiles of prefetch in flight across barriers
// (never drains to 0 in steady state). Raw s_barrier (no __syncthreads).
// Numerics identical to round 7 (fp16 QKV/QK^T; bf16 E and PV; no max
// subtraction — logits bounded ~55). Fragment maps (m89-verified):
// A/B: idx=lane&15, k=(lane>>4)*8+j;  C/D: col=lane&15, row=(lane>>4)*4+reg.
// [BK=32 => 64B LDS rows: fragment reads are bank-conflict-optimal unswizzled.]
// ---------------------------------------------------------------------------

typedef short    s16x8 __attribute__((ext_vector_type(8)));
typedef _Float16 h16x8 __attribute__((ext_vector_type(8)));
typedef _Float16 h16x4 __attribute__((ext_vector_type(4)));
typedef float    f32x4 __attribute__((ext_vector_type(4)));

__device__ __forceinline__ unsigned short f2bf(float x) {
    unsigned u = __float_as_uint(x);
    u += 0x7fffu + ((u >> 16) & 1u);          // RTNE
    return (unsigned short)(u >> 16);
}
__device__ __forceinline__ float bf2f(unsigned short h) {
    return __uint_as_float(((unsigned)h) << 16);
}
__device__ __forceinline__ unsigned short f2h(float x) {
    _Float16 h = (_Float16)x;                 // v_cvt_f16_f32, RTNE
    unsigned short u;
    __builtin_memcpy(&u, &h, 2);
    return u;
}
__device__ __forceinline__ h16x8 as_h(s16x8 v) {
    h16x8 r; __builtin_memcpy(&r, &v, 16); return r;
}

// async global->LDS, 16 B per lane; LDS dest = wave-uniform base + lane*16
__device__ __forceinline__ void gld16(const void* g, void* l) {
    __builtin_amdgcn_global_load_lds(
        (const __attribute__((address_space(1))) unsigned int*)(unsigned long long)g,
        (__attribute__((address_space(3))) unsigned int*)(unsigned)(unsigned long long)l,
        16, 0, 0);
}

template<bool FP16>
__device__ __forceinline__ f32x4 mma(s16x8 a, s16x8 b, f32x4 c) {
    if constexpr (FP16)
        return __builtin_amdgcn_mfma_f32_16x16x32_f16(as_h(a), as_h(b), c, 0, 0, 0);
    else
        return __builtin_amdgcn_mfma_f32_16x16x32_bf16(a, b, c, 0, 0, 0);
}

// NT GEMM, 512 thr = 8 waves (2Mx4N), tile 256x256, BK=32, 4-deep pipeline.
// MODE 1: C = acc + bias -> fp16        [K1a]
// MODE 2: C = acc + bias -> bf16        [K1b]
// MODE 3: C = exp(acc)   -> bf16        [K2]
// MODE 4: C = acc * rvec[row] -> f32    [K4]
// SWZ 0: none; 1: 3D batch-per-XCD; 2: 2D row-chunk-per-XCD (gridDim.y%8==0)
template<int MODE, bool FP16, int SWZ>
__global__ __launch_bounds__(512, 2)
void gemm_mfma(const unsigned short* __restrict__ A, const unsigned short* __restrict__ B,
               const float* __restrict__ bias, const float* __restrict__ rvec,
               float* __restrict__ Cf, unsigned short* __restrict__ Ch,
               int K, int lda, int ldb, int ldc,
               long long sA, long long sB, long long sC, long long sR)
{
    __shared__ unsigned short As[4][8192];    // 4 x [256 rows][32 k] 2B
    __shared__ unsigned short Bs[4][8192];

    int bx = blockIdx.x, by = blockIdx.y, bz = blockIdx.z;
    if (SWZ == 1) {
        const int l = bx + gridDim.x * (by + gridDim.y * bz);
        bz = l & 7;
        const int t = l >> 3;
        bx = t % gridDim.x;
        by = t / gridDim.x;
    } else if (SWZ == 2) {
        const int l = bx + gridDim.x * by;
        const int c = l & 7;
        const int t = l >> 3;
        const int rows = gridDim.y >> 3;
        bx = t % gridDim.x;
        by = c * rows + t / gridDim.x;
    }

    A += (long long)bz * sA;
    B += (long long)bz * sB;

    const long long m0 = (long long)by * 256;
    const long long n0 = (long long)bx * 256;

    const int tid  = threadIdx.x;
    const int wave = tid >> 6, lane = tid & 63;
    const int wr = wave >> 2, wc = wave & 3;             // 2M x 4N wave grid
    const int ml = lane & 15, kq = (lane >> 4) * 8;      // fragment map
    const int srr = wave * 16 + (lane >> 2);             // staging row 0..127
    const int skc = (lane & 3) * 8;                      // staging col (elems)

    const int aidx = (wr * 128 + ml) * 32 + kq;          // LDS elem index
    const int bidx = (wc * 64  + ml) * 32 + kq;

    const unsigned short* Abase = A + (m0 + srr) * (long long)lda + skc;
    const unsigned short* Bbase = B + (n0 + srr) * (long long)ldb + skc;
    const long long a128 = 128LL * lda, b128 = 128LL * ldb;

    // stage one 256x32 operand tile: 2 x (512 thr x 16B) = 16KB
    auto stage_a = [&](int t, int buf) {
        const unsigned short* p = Abase + t * 32;
        gld16(p,        &As[buf][wave * 512]);
        gld16(p + a128, &As[buf][4096 + wave * 512]);
    };
    auto stage_b = [&](int t, int buf) {
        const unsigned short* p = Bbase + t * 32;
        gld16(p,        &Bs[buf][wave * 512]);
        gld16(p + b128, &Bs[buf][4096 + wave * 512]);
    };

    f32x4 acc[8][4];
#pragma unroll
    for (int i = 0; i < 8; ++i)
#pragma unroll
        for (int j = 0; j < 4; ++j) acc[i][j] = f32x4{0.f, 0.f, 0.f, 0.f};

    const int nt = K >> 5;                    // K-tiles of 32 (>= 4 here)

    // prologue: stage tiles 0,1,2 (12 loads); tile0 ready at vmcnt(8)
    stage_a(0, 0); stage_b(0, 0);
    stage_a(1, 1); stage_b(1, 1);
    stage_a(2, 2); stage_b(2, 2);
    asm volatile("s_waitcnt vmcnt(8)");
    __builtin_amdgcn_s_barrier();

    for (int t = 0; t < nt; ++t) {
        const int cur = t & 3;
        const unsigned short* as = &As[cur][0];
        const unsigned short* bs = &Bs[cur][0];
        const bool pf = (t + 3 < nt);          // equivalent to t+4 <= nt
        const int nb = (t + 3) & 3;            // slot of tile t-1, freed last iter

        s16x8 a4[4], b4[4];

        // ---- phase A: frags for rows 0-63 of wave + all B; stage A(t+3)
#pragma unroll
        for (int i = 0; i < 4; ++i) a4[i] = *(const s16x8*)&as[aidx + i * 512];
#pragma unroll
        for (int j = 0; j < 4; ++j) b4[j] = *(const s16x8*)&bs[bidx + j * 512];
        if (pf) stage_a(t + 3, nb);
        __builtin_amdgcn_s_barrier();
        asm volatile("s_waitcnt lgkmcnt(0)");
        __builtin_amdgcn_sched_barrier(0);
        __builtin_amdgcn_s_setprio(1);
#pragma unroll
        for (int i = 0; i < 4; ++i)
#pragma unroll
            for (int j = 0; j < 4; ++j)
                acc[i][j] = mma<FP16>(a4[i], b4[j], acc[i][j]);
        __builtin_amdgcn_s_setprio(0);
        __builtin_amdgcn_s_barrier();

        // ---- phase B: frags for rows 64-127 (B reused); stage B(t+3)
#pragma unroll
        for (int i = 0; i < 4; ++i) a4[i] = *(const s16x8*)&as[aidx + (i + 4) * 512];
        if (pf) stage_b(t + 3, nb);
        __builtin_amdgcn_s_barrier();
        asm volatile("s_waitcnt lgkmcnt(0)");
        __builtin_amdgcn_sched_barrier(0);
        __builtin_amdgcn_s_setprio(1);
#pragma unroll
        for (int i = 0; i < 4; ++i)
#pragma unroll
            for (int j = 0; j < 4; ++j)
                acc[i + 4][j] = mma<FP16>(a4[i], b4[j], acc[i + 4][j]);
        __builtin_amdgcn_s_setprio(0);
        // counted vmcnt: guarantee tile t+1 resident; keep t+2,t+3 in flight
        if (pf)                { asm volatile("s_waitcnt vmcnt(8)"); }
        else if (t + 3 == nt)  { asm volatile("s_waitcnt vmcnt(4)"); }
        else if (t + 2 == nt)  { asm volatile("s_waitcnt vmcnt(0)"); }
        __builtin_amdgcn_s_barrier();
    }

    // ---- epilogue: C/D map col=lane&15, row=(lane>>4)*4+reg
    const int r0 = (lane >> 4) * 4;
    const long long rowbase = m0 + wr * 128 + r0;
    const long long colbase = n0 + wc * 64 + ml;
    if (MODE == 1 || MODE == 2) {
#pragma unroll
        for (int i = 0; i < 8; ++i) {
            const long long rowb = rowbase + i * 16;
#pragma unroll
            for (int j = 0; j < 4; ++j) {
                const long long col = colbase + j * 16;
                const float bj = bias[col];
#pragma unroll
                for (int q = 0; q < 4; ++q) {
                    const float vv = acc[i][j][q] + bj;
                    Ch[(rowb + q) * (long long)ldc + col] = (MODE == 1) ? f2h(vv) : f2bf(vv);
                }
            }
        }
    } else if (MODE == 3) {
        Ch += (long long)bz * sC;
#pragma unroll
        for (int i = 0; i < 8; ++i) {
            const long long rowb = rowbase + i * 16;
#pragma unroll
            for (int j = 0; j < 4; ++j) {
                const long long col = colbase + j * 16;
#pragma unroll
                for (int q = 0; q < 4; ++q)
                    Ch[(rowb + q) * (long long)ldc + col] = f2bf(__expf(acc[i][j][q]));
            }
        }
    } else {   // MODE 4
        Cf += (long long)bz * sC;
        rvec += (long long)bz * sR;
#pragma unroll
        for (int i = 0; i < 8; ++i) {
            const long long rowb = rowbase + i * 16;
#pragma unroll
            for (int j = 0; j < 4; ++j) {
                const long long col = colbase + j * 16;
#pragma unroll
                for (int q = 0; q < 4; ++q)
                    Cf[(rowb + q) * (long long)ldc + col] = acc[i][j][q] * rvec[rowb + q];
            }
        }
    }
}

// f32 -> fp16 convert, 4 elems/thread
__global__ __launch_bounds__(256)
void cvt_f16(const float* __restrict__ in, unsigned short* __restrict__ out, long long n4)
{
    const long long i = (long long)blockIdx.x * 256 + threadIdx.x;
    if (i >= n4) return;
    const float4 v = ((const float4*)in)[i];
    h16x4 o;
    o.x = (_Float16)v.x; o.y = (_Float16)v.y;
    o.z = (_Float16)v.z; o.w = (_Float16)v.w;
    ((h16x4*)out)[i] = o;
}

// vt[b][h][n] = v[b*2048+n][h]   (V transpose, bf16)
__global__ __launch_bounds__(256)
void transpose_v(const unsigned short* __restrict__ v, unsigned short* __restrict__ vt)
{
    __shared__ unsigned short t[32][33];
    const int b = blockIdx.z;
    const int n0 = blockIdx.x * 32, h0 = blockIdx.y * 32;
    const int tx = threadIdx.x, ty = threadIdx.y;      // 32 x 8
    const unsigned short* src = v + (long long)b * 2048 * 768;
#pragma unroll
    for (int q = 0; q < 4; ++q)
        t[ty + q * 8][tx] = src[(long long)(n0 + ty + q * 8) * 768 + h0 + tx];
    __syncthreads();
    unsigned short* dst = vt + ((long long)b * 768 + h0) * 2048 + n0;
#pragma unroll
    for (int q = 0; q < 4; ++q)
        dst[(long long)(ty + q * 8) * 2048 + tx] = t[tx][ty + q * 8];
}

// r[row] = 1 / sum(E[row][0:2048])   (E bf16, one 256-thr block per row)
__global__ __launch_bounds__(256)
void rowsum_recip(const unsigned short* __restrict__ E, float* __restrict__ r)
{
    const long long row = blockIdx.x;
    const int t = threadIdx.x, lane = t & 63, w = t >> 6;
    __shared__ float red[4];
    const uint4 v = ((const uint4*)(E + row * 2048))[t];   // 8 bf16
    float s = bf2f((unsigned short)(v.x & 0xffff)) + bf2f((unsigned short)(v.x >> 16))
            + bf2f((unsigned short)(v.y & 0xffff)) + bf2f((unsigned short)(v.y >> 16))
            + bf2f((unsigned short)(v.z & 0xffff)) + bf2f((unsigned short)(v.z >> 16))
            + bf2f((unsigned short)(v.w & 0xffff)) + bf2f((unsigned short)(v.w >> 16));
#pragma unroll
    for (int o = 32; o; o >>= 1) s += __shfl_xor(s, o);
    if (lane == 0) red[w] = s;
    __syncthreads();
    if (t == 0) r[row] = 1.f / ((red[0] + red[1]) + (red[2] + red[3]));
}

extern "C" void kernel_launch(void* const* d_in, const int* in_sizes, int n_in,
                              void* d_out, int out_size, void* d_ws, size_t ws_size,
                              hipStream_t stream)
{
    const float* x    = (const float*)d_in[0];   // [16384, 768]
    const float* W    = (const float*)d_in[1];   // [2304, 768]
    const float* bias = (const float*)d_in[2];   // [2304]
    float* out = (float*)d_out;                  // [8, 2048, 768]

    // ---- workspace layout (bytes), total 196.5 MB
    char* ws = (char*)d_ws;
    unsigned short* xh = (unsigned short*)ws;                      // [16384,768] fp16
    unsigned short* Wh = (unsigned short*)(ws + 25165824LL);       // [2304,768] fp16
    unsigned short* qk = (unsigned short*)(ws + 28704768LL);       // [16384,1536] fp16
    unsigned short* v  = (unsigned short*)(ws + 79036416LL);       // [16384,768] bf16
    unsigned short* vt = (unsigned short*)(ws + 104202240LL);      // [8,768,2048] bf16
    unsigned short* E  = (unsigned short*)(ws + 129368064LL);      // [8,2048,2048] bf16
    float*          r  = (float*)(ws + 196476928LL);               // [16384] f32

    // C1/C2: convert inputs to fp16
    cvt_f16<<<dim3(12288), dim3(256), 0, stream>>>(x, xh, 3145728LL);
    cvt_f16<<<dim3(1728),  dim3(256), 0, stream>>>(W, Wh, 442368LL);

    // K1a: qk = x @ Wqk^T + b  (fp16, M=16384 N=1536 K=768), 2D chunk swizzle
    gemm_mfma<1, true, 2><<<dim3(6, 64, 1), dim3(512), 0, stream>>>(
        xh, Wh, bias, nullptr, nullptr, qk,
        768, 768, 768, 1536, 0, 0, 0, 0);

    // K1b: v = x @ Wv^T + b -> bf16  (M=16384 N=768 K=768), 2D chunk swizzle
    gemm_mfma<2, true, 2><<<dim3(3, 64, 1), dim3(512), 0, stream>>>(
        xh, Wh + 1536LL * 768, bias + 1536, nullptr, nullptr, v,
        768, 768, 768, 768, 0, 0, 0, 0);

    // T: vt = v^T per batch
    transpose_v<<<dim3(64, 24, 8), dim3(32, 8), 0, stream>>>(v, vt);

    // K2: E = exp(q @ k^T)  (fp16, M=2048 N=2048 K=768, z=8), batch-per-XCD
    gemm_mfma<3, true, 1><<<dim3(8, 8, 8), dim3(512), 0, stream>>>(
        qk, qk + 768, nullptr, nullptr, nullptr, E,
        768, 1536, 1536, 2048,
        2048LL * 1536, 2048LL * 1536, 2048LL * 2048, 0);

    // K3': r = 1/rowsum(E)
    rowsum_recip<<<dim3(16384), dim3(256), 0, stream>>>(E, r);

    // K4: out = (E @ vt^T) * r[row]  (bf16, M=2048 N=768 K=2048, z=8), batch-per-XCD
    gemm_mfma<4, false, 1><<<dim3(3, 8, 8), dim3(512), 0, stream>>>(
        E, vt, nullptr, r, out, nullptr,
        2048, 2048, 2048, 768,
        2048LL * 2048, 768LL * 2048, 2048LL * 768, 2048);
}

// Round 2
// 337.101 us; speedup vs baseline: 1.0394x; 1.0394x over previous
//
#include <hip/hip_runtime.h>

// ---------------------------------------------------------------------------
// Attention_4956392259713 — round 9: swizzled LDS + single-barrier overlapped
// K-loop (fix round-8 serialization).
// qkv = x@W^T+b; S = q@k^T (unscaled); P = softmax(S); out = P@v
//
// Round-8 counters: MfmaUtil 26.6%, VALUBusy 12%, bank-conflict = 4 cyc per
// ds_read_b128 (4.7M/dispatch). Model: 4 barriers + 2 lgkmcnt(0) drains per
// K-tile serialize LDS reads (~1500 cyc/CU) against MFMAs (~620 cyc) with no
// overlap. Round 9:
//  (a) XOR swizzle for 64B rows: 16B-unit U = u ^ ((row>>1)&3). Write side
//      pre-swizzles the GLOBAL source column (gld16 LDS dest stays linear,
//      rule #21); read side folds the XOR into the per-lane constant ku.
//      Rows 0-7 now hit all 8 bank groups -> 2-way (free) instead of 8-way.
//  (b) One s_barrier per K-tile; NO manual lgkmcnt drains. All 12 ds_reads
//      issue first, compiler emits granular lgkm waits so MFMAs overlap the
//      tail reads. Counted vmcnt(8) ("memory" clobber) once per tile keeps
//      2 tiles of gld16 prefetch in flight across the barrier.
// Safety: every ds_read is consumed by an MFMA before the end-of-tile
// barrier (compiler waits), so slot (t+3)&3 = (t-1)&3 is re-stageable at
// iter t; vmcnt(8)+barrier publishes tile t+1 before iter t+1 reads it.
// Numerics identical (fp16 QKV/QK^T; bf16 E and PV; no max subtraction).
// Fragment maps (m89-verified): A/B idx=lane&15, k=(lane>>4)*8+j;
//                               C/D col=lane&15, row=(lane>>4)*4+reg.
// ---------------------------------------------------------------------------

typedef short    s16x8 __attribute__((ext_vector_type(8)));
typedef _Float16 h16x8 __attribute__((ext_vector_type(8)));
typedef _Float16 h16x4 __attribute__((ext_vector_type(4)));
typedef float    f32x4 __attribute__((ext_vector_type(4)));

__device__ __forceinline__ unsigned short f2bf(float x) {
    unsigned u = __float_as_uint(x);
    u += 0x7fffu + ((u >> 16) & 1u);          // RTNE
    return (unsigned short)(u >> 16);
}
__device__ __forceinline__ float bf2f(unsigned short h) {
    return __uint_as_float(((unsigned)h) << 16);
}
__device__ __forceinline__ unsigned short f2h(float x) {
    _Float16 h = (_Float16)x;                 // v_cvt_f16_f32, RTNE
    unsigned short u;
    __builtin_memcpy(&u, &h, 2);
    return u;
}
__device__ __forceinline__ h16x8 as_h(s16x8 v) {
    h16x8 r; __builtin_memcpy(&r, &v, 16); return r;
}

// async global->LDS, 16 B per lane; LDS dest = wave-uniform base + lane*16
__device__ __forceinline__ void gld16(const void* g, void* l) {
    __builtin_amdgcn_global_load_lds(
        (const __attribute__((address_space(1))) unsigned int*)(unsigned long long)g,
        (__attribute__((address_space(3))) unsigned int*)(unsigned)(unsigned long long)l,
        16, 0, 0);
}

template<bool FP16>
__device__ __forceinline__ f32x4 mma(s16x8 a, s16x8 b, f32x4 c) {
    if constexpr (FP16)
        return __builtin_amdgcn_mfma_f32_16x16x32_f16(as_h(a), as_h(b), c, 0, 0, 0);
    else
        return __builtin_amdgcn_mfma_f32_16x16x32_bf16(a, b, c, 0, 0, 0);
}

// NT GEMM, 512 thr = 8 waves (2Mx4N), tile 256x256, BK=32, 4-deep pipeline.
// MODE 1: C = acc + bias -> fp16        [K1a]
// MODE 2: C = acc + bias -> bf16        [K1b]
// MODE 3: C = exp(acc)   -> bf16        [K2]
// MODE 4: C = acc * rvec[row] -> f32    [K4]
// SWZ 0: none; 1: 3D batch-per-XCD; 2: 2D row-chunk-per-XCD (gridDim.y%8==0)
template<int MODE, bool FP16, int SWZ>
__global__ __launch_bounds__(512, 2)
void gemm_mfma(const unsigned short* __restrict__ A, const unsigned short* __restrict__ B,
               const float* __restrict__ bias, const float* __restrict__ rvec,
               float* __restrict__ Cf, unsigned short* __restrict__ Ch,
               int K, int lda, int ldb, int ldc,
               long long sA, long long sB, long long sC, long long sR)
{
    __shared__ unsigned short As[4][8192];    // 4 x [256 rows][32 k] 2B, swizzled
    __shared__ unsigned short Bs[4][8192];

    int bx = blockIdx.x, by = blockIdx.y, bz = blockIdx.z;
    if (SWZ == 1) {
        const int l = bx + gridDim.x * (by + gridDim.y * bz);
        bz = l & 7;
        const int t = l >> 3;
        bx = t % gridDim.x;
        by = t / gridDim.x;
    } else if (SWZ == 2) {
        const int l = bx + gridDim.x * by;
        const int c = l & 7;
        const int t = l >> 3;
        const int rows = gridDim.y >> 3;
        bx = t % gridDim.x;
        by = c * rows + t / gridDim.x;
    }

    A += (long long)bz * sA;
    B += (long long)bz * sB;

    const long long m0 = (long long)by * 256;
    const long long n0 = (long long)bx * 256;

    const int tid  = threadIdx.x;
    const int wave = tid >> 6, lane = tid & 63;
    const int wr = wave >> 2, wc = wave & 3;             // 2M x 4N wave grid
    const int ml = lane & 15;                            // fragment row-in-16
    // swizzled k-unit for fragment reads: U = u ^ ((row>>1)&3); row bases are
    // multiples of 16 so (row>>1)&3 == (ml>>1)&3 -> per-lane constant.
    const int ku = (((lane >> 4) ^ ((ml >> 1) & 3)) * 8);
    const int srr = wave * 16 + (lane >> 2);             // staging row 0..127
    // pre-swizzled GLOBAL column: slot (r,U) holds global unit u = U^((r>>1)&3),
    // with r = wave*16 + (lane>>2) -> (r>>1)&3 == (lane>>3)&3.
    const int skc = (((lane & 3) ^ ((lane >> 3) & 3)) * 8);

    const int aidx = (wr * 128 + ml) * 32 + ku;          // LDS elem index
    const int bidx = (wc * 64  + ml) * 32 + ku;

    const unsigned short* Abase = A + (m0 + srr) * (long long)lda + skc;
    const unsigned short* Bbase = B + (n0 + srr) * (long long)ldb + skc;
    const long long a128 = 128LL * lda, b128 = 128LL * ldb;

    // stage one 256x32 operand tile: 2 x (512 thr x 16B) = 16KB
    auto stage_a = [&](int t, int buf) {
        const unsigned short* p = Abase + t * 32;
        gld16(p,        &As[buf][wave * 512]);
        gld16(p + a128, &As[buf][4096 + wave * 512]);
    };
    auto stage_b = [&](int t, int buf) {
        const unsigned short* p = Bbase + t * 32;
        gld16(p,        &Bs[buf][wave * 512]);
        gld16(p + b128, &Bs[buf][4096 + wave * 512]);
    };

    f32x4 acc[8][4];
#pragma unroll
    for (int i = 0; i < 8; ++i)
#pragma unroll
        for (int j = 0; j < 4; ++j) acc[i][j] = f32x4{0.f, 0.f, 0.f, 0.f};

    const int nt = K >> 5;                    // K-tiles of 32 (>= 4 here)

    // prologue: stage tiles 0,1,2 (12 loads); tile0 ready at vmcnt(8)
    stage_a(0, 0); stage_b(0, 0);
    stage_a(1, 1); stage_b(1, 1);
    stage_a(2, 2); stage_b(2, 2);
    asm volatile("s_waitcnt vmcnt(8)" ::: "memory");
    __builtin_amdgcn_s_barrier();
    __builtin_amdgcn_sched_barrier(0);

    for (int t = 0; t < nt; ++t) {
        const int cur = t & 3;
        const unsigned short* as = &As[cur][0];
        const unsigned short* bs = &Bs[cur][0];
        const bool pf = (t + 3 < nt);
        const int nb = (t + 3) & 3;            // slot of tile t-1, freed last iter

        s16x8 a8[8], b4[4];
        // issue all 12 ds_reads; compiler emits granular lgkm waits so the
        // MFMA cluster below overlaps the tail reads.
#pragma unroll
        for (int i = 0; i < 4; ++i) a8[i] = *(const s16x8*)&as[aidx + i * 512];
#pragma unroll
        for (int j = 0; j < 4; ++j) b4[j] = *(const s16x8*)&bs[bidx + j * 512];
#pragma unroll
        for (int i = 0; i < 4; ++i) a8[4 + i] = *(const s16x8*)&as[aidx + (i + 4) * 512];

        // prefetch tile t+3 into the slot freed at the end of iter t-1
        if (pf) { stage_a(t + 3, nb); stage_b(t + 3, nb); }

        __builtin_amdgcn_s_setprio(1);
#pragma unroll
        for (int i = 0; i < 8; ++i)
#pragma unroll
            for (int j = 0; j < 4; ++j)
                acc[i][j] = mma<FP16>(a8[i], b4[j], acc[i][j]);
        __builtin_amdgcn_s_setprio(0);

        // counted vmcnt: tile t+1 resident; keep t+2,t+3 in flight
        if (pf)                { asm volatile("s_waitcnt vmcnt(8)" ::: "memory"); }
        else if (t + 3 == nt)  { asm volatile("s_waitcnt vmcnt(4)" ::: "memory"); }
        else if (t + 2 == nt)  { asm volatile("s_waitcnt vmcnt(0)" ::: "memory"); }
        __builtin_amdgcn_s_barrier();
        __builtin_amdgcn_sched_barrier(0);
    }

    // ---- epilogue: C/D map col=lane&15, row=(lane>>4)*4+reg
    const int r0 = (lane >> 4) * 4;
    const long long rowbase = m0 + wr * 128 + r0;
    const long long colbase = n0 + wc * 64 + ml;
    if (MODE == 1 || MODE == 2) {
#pragma unroll
        for (int i = 0; i < 8; ++i) {
            const long long rowb = rowbase + i * 16;
#pragma unroll
            for (int j = 0; j < 4; ++j) {
                const long long col = colbase + j * 16;
                const float bj = bias[col];
#pragma unroll
                for (int q = 0; q < 4; ++q) {
                    const float vv = acc[i][j][q] + bj;
                    Ch[(rowb + q) * (long long)ldc + col] = (MODE == 1) ? f2h(vv) : f2bf(vv);
                }
            }
        }
    } else if (MODE == 3) {
        Ch += (long long)bz * sC;
#pragma unroll
        for (int i = 0; i < 8; ++i) {
            const long long rowb = rowbase + i * 16;
#pragma unroll
            for (int j = 0; j < 4; ++j) {
                const long long col = colbase + j * 16;
#pragma unroll
                for (int q = 0; q < 4; ++q)
                    Ch[(rowb + q) * (long long)ldc + col] = f2bf(__expf(acc[i][j][q]));
            }
        }
    } else {   // MODE 4
        Cf += (long long)bz * sC;
        rvec += (long long)bz * sR;
#pragma unroll
        for (int i = 0; i < 8; ++i) {
            const long long rowb = rowbase + i * 16;
#pragma unroll
            for (int j = 0; j < 4; ++j) {
                const long long col = colbase + j * 16;
#pragma unroll
                for (int q = 0; q < 4; ++q)
                    Cf[(rowb + q) * (long long)ldc + col] = acc[i][j][q] * rvec[rowb + q];
            }
        }
    }
}

// f32 -> fp16 convert, 4 elems/thread
__global__ __launch_bounds__(256)
void cvt_f16(const float* __restrict__ in, unsigned short* __restrict__ out, long long n4)
{
    const long long i = (long long)blockIdx.x * 256 + threadIdx.x;
    if (i >= n4) return;
    const float4 v = ((const float4*)in)[i];
    h16x4 o;
    o.x = (_Float16)v.x; o.y = (_Float16)v.y;
    o.z = (_Float16)v.z; o.w = (_Float16)v.w;
    ((h16x4*)out)[i] = o;
}

// vt[b][h][n] = v[b*2048+n][h]   (V transpose, bf16)
__global__ __launch_bounds__(256)
void transpose_v(const unsigned short* __restrict__ v, unsigned short* __restrict__ vt)
{
    __shared__ unsigned short t[32][33];
    const int b = blockIdx.z;
    const int n0 = blockIdx.x * 32, h0 = blockIdx.y * 32;
    const int tx = threadIdx.x, ty = threadIdx.y;      // 32 x 8
    const unsigned short* src = v + (long long)b * 2048 * 768;
#pragma unroll
    for (int q = 0; q < 4; ++q)
        t[ty + q * 8][tx] = src[(long long)(n0 + ty + q * 8) * 768 + h0 + tx];
    __syncthreads();
    unsigned short* dst = vt + ((long long)b * 768 + h0) * 2048 + n0;
#pragma unroll
    for (int q = 0; q < 4; ++q)
        dst[(long long)(ty + q * 8) * 2048 + tx] = t[tx][ty + q * 8];
}

// r[row] = 1 / sum(E[row][0:2048])   (E bf16, one 256-thr block per row)
__global__ __launch_bounds__(256)
void rowsum_recip(const unsigned short* __restrict__ E, float* __restrict__ r)
{
    const long long row = blockIdx.x;
    const int t = threadIdx.x, lane = t & 63, w = t >> 6;
    __shared__ float red[4];
    const uint4 v = ((const uint4*)(E + row * 2048))[t];   // 8 bf16
    float s = bf2f((unsigned short)(v.x & 0xffff)) + bf2f((unsigned short)(v.x >> 16))
            + bf2f((unsigned short)(v.y & 0xffff)) + bf2f((unsigned short)(v.y >> 16))
            + bf2f((unsigned short)(v.z & 0xffff)) + bf2f((unsigned short)(v.z >> 16))
            + bf2f((unsigned short)(v.w & 0xffff)) + bf2f((unsigned short)(v.w >> 16));
#pragma unroll
    for (int o = 32; o; o >>= 1) s += __shfl_xor(s, o);
    if (lane == 0) red[w] = s;
    __syncthreads();
    if (t == 0) r[row] = 1.f / ((red[0] + red[1]) + (red[2] + red[3]));
}

extern "C" void kernel_launch(void* const* d_in, const int* in_sizes, int n_in,
                              void* d_out, int out_size, void* d_ws, size_t ws_size,
                              hipStream_t stream)
{
    const float* x    = (const float*)d_in[0];   // [16384, 768]
    const float* W    = (const float*)d_in[1];   // [2304, 768]
    const float* bias = (const float*)d_in[2];   // [2304]
    float* out = (float*)d_out;                  // [8, 2048, 768]

    // ---- workspace layout (bytes), total 196.5 MB
    char* ws = (char*)d_ws;
    unsigned short* xh = (unsigned short*)ws;                      // [16384,768] fp16
    unsigned short* Wh = (unsigned short*)(ws + 25165824LL);       // [2304,768] fp16
    unsigned short* qk = (unsigned short*)(ws + 28704768LL);       // [16384,1536] fp16
    unsigned short* v  = (unsigned short*)(ws + 79036416LL);       // [16384,768] bf16
    unsigned short* vt = (unsigned short*)(ws + 104202240LL);      // [8,768,2048] bf16
    unsigned short* E  = (unsigned short*)(ws + 129368064LL);      // [8,2048,2048] bf16
    float*          r  = (float*)(ws + 196476928LL);               // [16384] f32

    // C1/C2: convert inputs to fp16
    cvt_f16<<<dim3(12288), dim3(256), 0, stream>>>(x, xh, 3145728LL);
    cvt_f16<<<dim3(1728),  dim3(256), 0, stream>>>(W, Wh, 442368LL);

    // K1a: qk = x @ Wqk^T + b  (fp16, M=16384 N=1536 K=768), 2D chunk swizzle
    gemm_mfma<1, true, 2><<<dim3(6, 64, 1), dim3(512), 0, stream>>>(
        xh, Wh, bias, nullptr, nullptr, qk,
        768, 768, 768, 1536, 0, 0, 0, 0);

    // K1b: v = x @ Wv^T + b -> bf16  (M=16384 N=768 K=768), 2D chunk swizzle
    gemm_mfma<2, true, 2><<<dim3(3, 64, 1), dim3(512), 0, stream>>>(
        xh, Wh + 1536LL * 768, bias + 1536, nullptr, nullptr, v,
        768, 768, 768, 768, 0, 0, 0, 0);

    // T: vt = v^T per batch
    transpose_v<<<dim3(64, 24, 8), dim3(32, 8), 0, stream>>>(v, vt);

    // K2: E = exp(q @ k^T)  (fp16, M=2048 N=2048 K=768, z=8), batch-per-XCD
    gemm_mfma<3, true, 1><<<dim3(8, 8, 8), dim3(512), 0, stream>>>(
        qk, qk + 768, nullptr, nullptr, nullptr, E,
        768, 1536, 1536, 2048,
        2048LL * 1536, 2048LL * 1536, 2048LL * 2048, 0);

    // K3': r = 1/rowsum(E)
    rowsum_recip<<<dim3(16384), dim3(256), 0, stream>>>(E, r);

    // K4: out = (E @ vt^T) * r[row]  (bf16, M=2048 N=768 K=2048, z=8), batch-per-XCD
    gemm_mfma<4, false, 1><<<dim3(3, 8, 8), dim3(512), 0, stream>>>(
        E, vt, nullptr, r, out, nullptr,
        2048, 2048, 2048, 768,
        2048LL * 2048, 768LL * 2048, 2048LL * 768, 2048);
}

// Round 3
// 326.226 us; speedup vs baseline: 1.0740x; 1.0333x over previous
//
#include <hip/hip_runtime.h>

// ---------------------------------------------------------------------------
// Attention_4956392259713 — round 10: full 8-phase (m201-style) GEMM schedule.
// qkv = x@W^T+b; S = q@k^T (unscaled); P = softmax(S); out = P@v
//
// Round-9 counters: bank-conflict 0 (swizzle verified), K2 66us/781TF but
// MfmaUtil only 30.5% -> coarse 1-phase/K-tile schedule serializes the LDS
// window (~1150cyc/CU) against the MFMA window (~1240cyc/SIMD). Catalog gate:
// T2/T4/T5 pay only inside the fine-phase schedule (m196/m218/m233).
// Round-10 core (template port, BK=64, 2-buf LDS 128KB, 8 waves 2Mx4N,
// per-wave C 128x64, 4 phases/K-tile, 16 MFMA/phase):
//   ph1: read A-h0 (8 b128) + B-h0 (4); stage next{A-h0,B-h0}; bar;
//        lgkm0; prio1; 16 MFMA (acc[0][.][0:1]); prio0; vmcnt(6); bar
//   ph2: read B-h1 (4); stage next{B-h1}; bar; ...16 MFMA acc[0][.][2:3];
//        vmcnt(6); bar
//   ph3: read A-h1 (8); stage next{A-h1}; bar; ...16 MFMA acc[1][.][2:3]; bar
//   ph4: (regs reused); bar; ...16 MFMA acc[1][.][0:1]; vmcnt(4); bar
// FIFO bookkeeping (2 loads/half-tile): entering ph1 outstanding =
// {Bh1,Ah1}(4); ph1 +4 -> vmcnt(6) drains Bh1 (read at ph2); ph2 +2 ->
// vmcnt(6) drains Ah1 (read at ph3); ph4 -> vmcnt(4) drains {Ah0',Bh0'}
// (read next ph1). Never drains to 0 in steady state (T4). Overwrite-safe:
// every stage targets the buffer fully consumed by end of previous iter.
// Swizzle (128B rows, 8 16B-units): U' = U ^ (row&7); write side = linear
// gld16 dest + pre-swizzled global column ((lane&7)^(lane>>3))*8 (rule #21);
// read side folded into per-lane constants ua0/ua1. 2-way = free.
// Numerics identical (fp16 QKV/QK^T; bf16 E and PV; no max subtraction).
// Fragment maps (m89-verified): A/B idx=lane&15, k=(lane>>4)*8+j;
//                               C/D col=lane&15, row=(lane>>4)*4+reg.
// ---------------------------------------------------------------------------

typedef short    s16x8 __attribute__((ext_vector_type(8)));
typedef _Float16 h16x8 __attribute__((ext_vector_type(8)));
typedef _Float16 h16x4 __attribute__((ext_vector_type(4)));
typedef float    f32x4 __attribute__((ext_vector_type(4)));

__device__ __forceinline__ unsigned short f2bf(float x) {
    unsigned u = __float_as_uint(x);
    u += 0x7fffu + ((u >> 16) & 1u);          // RTNE
    return (unsigned short)(u >> 16);
}
__device__ __forceinline__ float bf2f(unsigned short h) {
    return __uint_as_float(((unsigned)h) << 16);
}
__device__ __forceinline__ unsigned short f2h(float x) {
    _Float16 h = (_Float16)x;                 // v_cvt_f16_f32, RTNE
    unsigned short u;
    __builtin_memcpy(&u, &h, 2);
    return u;
}
__device__ __forceinline__ h16x8 as_h(s16x8 v) {
    h16x8 r; __builtin_memcpy(&r, &v, 16); return r;
}

// async global->LDS, 16 B per lane; LDS dest = wave-uniform base + lane*16
__device__ __forceinline__ void gld16(const void* g, void* l) {
    __builtin_amdgcn_global_load_lds(
        (const __attribute__((address_space(1))) unsigned int*)(unsigned long long)g,
        (__attribute__((address_space(3))) unsigned int*)(unsigned)(unsigned long long)l,
        16, 0, 0);
}

template<bool FP16>
__device__ __forceinline__ f32x4 mma(s16x8 a, s16x8 b, f32x4 c) {
    if constexpr (FP16)
        return __builtin_amdgcn_mfma_f32_16x16x32_f16(as_h(a), as_h(b), c, 0, 0, 0);
    else
        return __builtin_amdgcn_mfma_f32_16x16x32_bf16(a, b, c, 0, 0, 0);
}

// NT GEMM, 512 thr = 8 waves (2Mx4N), tile 256x256, BK=64, 2-buf 8-phase.
// MODE 1: C = acc + bias -> fp16        [K1a]
// MODE 2: C = acc + bias -> bf16        [K1b]
// MODE 3: C = exp(acc)   -> bf16        [K2]
// MODE 4: C = acc * rvec[row] -> f32    [K4]
// SWZ 0: none; 1: 3D batch-per-XCD; 2: 2D row-chunk-per-XCD (gridDim.y%8==0)
template<int MODE, bool FP16, int SWZ>
__global__ __launch_bounds__(512, 2)
void gemm_mfma(const unsigned short* __restrict__ A, const unsigned short* __restrict__ B,
               const float* __restrict__ bias, const float* __restrict__ rvec,
               float* __restrict__ Cf, unsigned short* __restrict__ Ch,
               int K, int lda, int ldb, int ldc,
               long long sA, long long sB, long long sC, long long sR)
{
    __shared__ unsigned short As[2][16384];   // 2 x [256 rows][64 k] 2B, swizzled
    __shared__ unsigned short Bs[2][16384];

    int bx = blockIdx.x, by = blockIdx.y, bz = blockIdx.z;
    if (SWZ == 1) {
        const int l = bx + gridDim.x * (by + gridDim.y * bz);
        bz = l & 7;
        const int t = l >> 3;
        bx = t % gridDim.x;
        by = t / gridDim.x;
    } else if (SWZ == 2) {
        const int l = bx + gridDim.x * by;
        const int c = l & 7;
        const int t = l >> 3;
        const int rows = gridDim.y >> 3;
        bx = t % gridDim.x;
        by = c * rows + t / gridDim.x;
    }

    A += (long long)bz * sA;
    B += (long long)bz * sB;

    const long long m0 = (long long)by * 256;
    const long long n0 = (long long)bx * 256;

    const int tid  = threadIdx.x;
    const int wave = tid >> 6, lane = tid & 63;
    const int wr = wave >> 2, wc = wave & 3;             // 2M x 4N wave grid
    const int ml = lane & 15, kq4 = lane >> 4;           // fragment map
    // swizzled k-units (16B) for fragment reads: U' = U ^ (row&7), row&7==ml&7
    const int ua0 = ((kq4)     ^ (ml & 7)) * 8;          // kstep 0, elems
    const int ua1 = ((4 + kq4) ^ (ml & 7)) * 8;          // kstep 1
    // staging: lane -> row-in-8 srow, pre-swizzled global column unit
    const int srow = lane >> 3;                          // 0..7
    const int skc  = ((lane & 7) ^ srow) * 8;            // elems

    const int aoff = (wr * 64 + ml) * 64;                // elem base within half
    const int boff = (wc * 32 + ml) * 64;

    // stage one 16KB half-tile (128 rows x 64 k): 2 gld16/thread, linear dest
    auto stA = [&](int kt, int b, int h) {
#pragma unroll
        for (int q = 0; q < 2; ++q)
            gld16(A + (m0 + h * 128 + q * 64 + wave * 8 + srow) * (long long)lda + kt * 64 + skc,
                  (char*)&As[b][0] + h * 16384 + q * 8192 + wave * 1024);
    };
    auto stB = [&](int kt, int b, int h) {
#pragma unroll
        for (int q = 0; q < 2; ++q)
            gld16(B + (n0 + h * 128 + q * 64 + wave * 8 + srow) * (long long)ldb + kt * 64 + skc,
                  (char*)&Bs[b][0] + h * 16384 + q * 8192 + wave * 1024);
    };

    f32x4 acc[2][4][4];
#pragma unroll
    for (int r = 0; r < 2; ++r)
#pragma unroll
        for (int i = 0; i < 4; ++i)
#pragma unroll
            for (int j = 0; j < 4; ++j) acc[r][i][j] = f32x4{0.f, 0.f, 0.f, 0.f};

    const int nit = K >> 6;                   // K-tiles of 64 (>= 12 here)

    // prologue: stage buf0 in first-use order Ah0,Bh0,Bh1,Ah1 (8 loads)
    stA(0, 0, 0); stB(0, 0, 0); stB(0, 0, 1); stA(0, 0, 1);
    asm volatile("s_waitcnt vmcnt(4)" ::: "memory");   // Ah0,Bh0 resident
    __builtin_amdgcn_s_barrier();
    __builtin_amdgcn_sched_barrier(0);

    s16x8 af[4][2], bf0[2][2], bf1[2][2];

    for (int it = 0; it < nit; ++it) {
        const int cur = it & 1, nb = cur ^ 1;
        const unsigned short* as = &As[cur][0];
        const unsigned short* bs = &Bs[cur][0];
        const bool pf = (it + 1 < nit);
        const int kt1 = it + 1;

        // ---- phase 1: A-h0 (8) + B-h0 (4); stage next Ah0+Bh0
#pragma unroll
        for (int i = 0; i < 4; ++i) {
            af[i][0] = *(const s16x8*)&as[aoff + i * 1024 + ua0];
            af[i][1] = *(const s16x8*)&as[aoff + i * 1024 + ua1];
        }
#pragma unroll
        for (int j = 0; j < 2; ++j) {
            bf0[j][0] = *(const s16x8*)&bs[boff + j * 1024 + ua0];
            bf0[j][1] = *(const s16x8*)&bs[boff + j * 1024 + ua1];
        }
        if (pf) { stA(kt1, nb, 0); stB(kt1, nb, 0); }
        __builtin_amdgcn_s_barrier();
        asm volatile("s_waitcnt lgkmcnt(0)" ::: "memory");
        __builtin_amdgcn_sched_barrier(0);
        __builtin_amdgcn_s_setprio(1);
#pragma unroll
        for (int s = 0; s < 2; ++s)
#pragma unroll
            for (int i = 0; i < 4; ++i)
#pragma unroll
                for (int j = 0; j < 2; ++j)
                    acc[0][i][j] = mma<FP16>(af[i][s], bf0[j][s], acc[0][i][j]);
        __builtin_amdgcn_s_setprio(0);
        if (pf) { asm volatile("s_waitcnt vmcnt(6)" ::: "memory"); }   // Bh1 ready
        else    { asm volatile("s_waitcnt vmcnt(2)" ::: "memory"); }
        __builtin_amdgcn_s_barrier();
        __builtin_amdgcn_sched_barrier(0);

        // ---- phase 2: B-h1 (4); stage next Bh1
#pragma unroll
        for (int j = 0; j < 2; ++j) {
            bf1[j][0] = *(const s16x8*)&bs[8192 + boff + j * 1024 + ua0];
            bf1[j][1] = *(const s16x8*)&bs[8192 + boff + j * 1024 + ua1];
        }
        if (pf) { stB(kt1, nb, 1); }
        __builtin_amdgcn_s_barrier();
        asm volatile("s_waitcnt lgkmcnt(0)" ::: "memory");
        __builtin_amdgcn_sched_barrier(0);
        __builtin_amdgcn_s_setprio(1);
#pragma unroll
        for (int s = 0; s < 2; ++s)
#pragma unroll
            for (int i = 0; i < 4; ++i)
#pragma unroll
                for (int j = 0; j < 2; ++j)
                    acc[0][i][2 + j] = mma<FP16>(af[i][s], bf1[j][s], acc[0][i][2 + j]);
        __builtin_amdgcn_s_setprio(0);
        if (pf) { asm volatile("s_waitcnt vmcnt(6)" ::: "memory"); }   // Ah1 ready
        else    { asm volatile("s_waitcnt vmcnt(0)" ::: "memory"); }
        __builtin_amdgcn_s_barrier();
        __builtin_amdgcn_sched_barrier(0);

        // ---- phase 3: A-h1 (8); stage next Ah1
#pragma unroll
        for (int i = 0; i < 4; ++i) {
            af[i][0] = *(const s16x8*)&as[8192 + aoff + i * 1024 + ua0];
            af[i][1] = *(const s16x8*)&as[8192 + aoff + i * 1024 + ua1];
        }
        if (pf) { stA(kt1, nb, 1); }
        __builtin_amdgcn_s_barrier();
        asm volatile("s_waitcnt lgkmcnt(0)" ::: "memory");
        __builtin_amdgcn_sched_barrier(0);
        __builtin_amdgcn_s_setprio(1);
#pragma unroll
        for (int s = 0; s < 2; ++s)
#pragma unroll
            for (int i = 0; i < 4; ++i)
#pragma unroll
                for (int j = 0; j < 2; ++j)
                    acc[1][i][2 + j] = mma<FP16>(af[i][s], bf1[j][s], acc[1][i][2 + j]);
        __builtin_amdgcn_s_setprio(0);
        __builtin_amdgcn_s_barrier();
        __builtin_amdgcn_sched_barrier(0);

        // ---- phase 4: no reads (bf0 retained)
        __builtin_amdgcn_s_barrier();
        __builtin_amdgcn_s_setprio(1);
#pragma unroll
        for (int s = 0; s < 2; ++s)
#pragma unroll
            for (int i = 0; i < 4; ++i)
#pragma unroll
                for (int j = 0; j < 2; ++j)
                    acc[1][i][j] = mma<FP16>(af[i][s], bf0[j][s], acc[1][i][j]);
        __builtin_amdgcn_s_setprio(0);
        if (pf) { asm volatile("s_waitcnt vmcnt(4)" ::: "memory"); }   // next Ah0,Bh0
        __builtin_amdgcn_s_barrier();
        __builtin_amdgcn_sched_barrier(0);
    }

    // ---- epilogue: C/D map col=lane&15, row=(lane>>4)*4+reg
    const int r0 = (lane >> 4) * 4;
    if (MODE == 1 || MODE == 2) {
#pragma unroll
        for (int rh = 0; rh < 2; ++rh)
#pragma unroll
            for (int i = 0; i < 4; ++i) {
                const long long rowb = m0 + rh * 128 + wr * 64 + i * 16 + r0;
#pragma unroll
                for (int jg = 0; jg < 4; ++jg) {
                    const long long col = n0 + (jg >> 1) * 128 + wc * 32 + (jg & 1) * 16 + ml;
                    const float bj = bias[col];
#pragma unroll
                    for (int q = 0; q < 4; ++q) {
                        const float vv = acc[rh][i][jg][q] + bj;
                        Ch[(rowb + q) * (long long)ldc + col] = (MODE == 1) ? f2h(vv) : f2bf(vv);
                    }
                }
            }
    } else if (MODE == 3) {
        Ch += (long long)bz * sC;
#pragma unroll
        for (int rh = 0; rh < 2; ++rh)
#pragma unroll
            for (int i = 0; i < 4; ++i) {
                const long long rowb = m0 + rh * 128 + wr * 64 + i * 16 + r0;
#pragma unroll
                for (int jg = 0; jg < 4; ++jg) {
                    const long long col = n0 + (jg >> 1) * 128 + wc * 32 + (jg & 1) * 16 + ml;
#pragma unroll
                    for (int q = 0; q < 4; ++q)
                        Ch[(rowb + q) * (long long)ldc + col] = f2bf(__expf(acc[rh][i][jg][q]));
                }
            }
    } else {   // MODE 4
        Cf += (long long)bz * sC;
        rvec += (long long)bz * sR;
#pragma unroll
        for (int rh = 0; rh < 2; ++rh)
#pragma unroll
            for (int i = 0; i < 4; ++i) {
                const long long rowb = m0 + rh * 128 + wr * 64 + i * 16 + r0;
#pragma unroll
                for (int jg = 0; jg < 4; ++jg) {
                    const long long col = n0 + (jg >> 1) * 128 + wc * 32 + (jg & 1) * 16 + ml;
#pragma unroll
                    for (int q = 0; q < 4; ++q)
                        Cf[(rowb + q) * (long long)ldc + col] = acc[rh][i][jg][q] * rvec[rowb + q];
                }
            }
    }
}

// f32 -> fp16 convert, 4 elems/thread
__global__ __launch_bounds__(256)
void cvt_f16(const float* __restrict__ in, unsigned short* __restrict__ out, long long n4)
{
    const long long i = (long long)blockIdx.x * 256 + threadIdx.x;
    if (i >= n4) return;
    const float4 v = ((const float4*)in)[i];
    h16x4 o;
    o.x = (_Float16)v.x; o.y = (_Float16)v.y;
    o.z = (_Float16)v.z; o.w = (_Float16)v.w;
    ((h16x4*)out)[i] = o;
}

// vt[b][h][n] = v[b*2048+n][h]   (V transpose, bf16)
__global__ __launch_bounds__(256)
void transpose_v(const unsigned short* __restrict__ v, unsigned short* __restrict__ vt)
{
    __shared__ unsigned short t[32][33];
    const int b = blockIdx.z;
    const int n0 = blockIdx.x * 32, h0 = blockIdx.y * 32;
    const int tx = threadIdx.x, ty = threadIdx.y;      // 32 x 8
    const unsigned short* src = v + (long long)b * 2048 * 768;
#pragma unroll
    for (int q = 0; q < 4; ++q)
        t[ty + q * 8][tx] = src[(long long)(n0 + ty + q * 8) * 768 + h0 + tx];
    __syncthreads();
    unsigned short* dst = vt + ((long long)b * 768 + h0) * 2048 + n0;
#pragma unroll
    for (int q = 0; q < 4; ++q)
        dst[(long long)(ty + q * 8) * 2048 + tx] = t[tx][ty + q * 8];
}

// r[row] = 1 / sum(E[row][0:2048])   (E bf16, one 256-thr block per row)
__global__ __launch_bounds__(256)
void rowsum_recip(const unsigned short* __restrict__ E, float* __restrict__ r)
{
    const long long row = blockIdx.x;
    const int t = threadIdx.x, lane = t & 63, w = t >> 6;
    __shared__ float red[4];
    const uint4 v = ((const uint4*)(E + row * 2048))[t];   // 8 bf16
    float s = bf2f((unsigned short)(v.x & 0xffff)) + bf2f((unsigned short)(v.x >> 16))
            + bf2f((unsigned short)(v.y & 0xffff)) + bf2f((unsigned short)(v.y >> 16))
            + bf2f((unsigned short)(v.z & 0xffff)) + bf2f((unsigned short)(v.z >> 16))
            + bf2f((unsigned short)(v.w & 0xffff)) + bf2f((unsigned short)(v.w >> 16));
#pragma unroll
    for (int o = 32; o; o >>= 1) s += __shfl_xor(s, o);
    if (lane == 0) red[w] = s;
    __syncthreads();
    if (t == 0) r[row] = 1.f / ((red[0] + red[1]) + (red[2] + red[3]));
}

extern "C" void kernel_launch(void* const* d_in, const int* in_sizes, int n_in,
                              void* d_out, int out_size, void* d_ws, size_t ws_size,
                              hipStream_t stream)
{
    const float* x    = (const float*)d_in[0];   // [16384, 768]
    const float* W    = (const float*)d_in[1];   // [2304, 768]
    const float* bias = (const float*)d_in[2];   // [2304]
    float* out = (float*)d_out;                  // [8, 2048, 768]

    // ---- workspace layout (bytes), total 196.5 MB
    char* ws = (char*)d_ws;
    unsigned short* xh = (unsigned short*)ws;                      // [16384,768] fp16
    unsigned short* Wh = (unsigned short*)(ws + 25165824LL);       // [2304,768] fp16
    unsigned short* qk = (unsigned short*)(ws + 28704768LL);       // [16384,1536] fp16
    unsigned short* v  = (unsigned short*)(ws + 79036416LL);       // [16384,768] bf16
    unsigned short* vt = (unsigned short*)(ws + 104202240LL);      // [8,768,2048] bf16
    unsigned short* E  = (unsigned short*)(ws + 129368064LL);      // [8,2048,2048] bf16
    float*          r  = (float*)(ws + 196476928LL);               // [16384] f32

    // C1/C2: convert inputs to fp16
    cvt_f16<<<dim3(12288), dim3(256), 0, stream>>>(x, xh, 3145728LL);
    cvt_f16<<<dim3(1728),  dim3(256), 0, stream>>>(W, Wh, 442368LL);

    // K1a: qk = x @ Wqk^T + b  (fp16, M=16384 N=1536 K=768), 2D chunk swizzle
    gemm_mfma<1, true, 2><<<dim3(6, 64, 1), dim3(512), 0, stream>>>(
        xh, Wh, bias, nullptr, nullptr, qk,
        768, 768, 768, 1536, 0, 0, 0, 0);

    // K1b: v = x @ Wv^T + b -> bf16  (M=16384 N=768 K=768), 2D chunk swizzle
    gemm_mfma<2, true, 2><<<dim3(3, 64, 1), dim3(512), 0, stream>>>(
        xh, Wh + 1536LL * 768, bias + 1536, nullptr, nullptr, v,
        768, 768, 768, 768, 0, 0, 0, 0);

    // T: vt = v^T per batch
    transpose_v<<<dim3(64, 24, 8), dim3(32, 8), 0, stream>>>(v, vt);

    // K2: E = exp(q @ k^T)  (fp16, M=2048 N=2048 K=768, z=8), batch-per-XCD
    gemm_mfma<3, true, 1><<<dim3(8, 8, 8), dim3(512), 0, stream>>>(
        qk, qk + 768, nullptr, nullptr, nullptr, E,
        768, 1536, 1536, 2048,
        2048LL * 1536, 2048LL * 1536, 2048LL * 2048, 0);

    // K3': r = 1/rowsum(E)
    rowsum_recip<<<dim3(16384), dim3(256), 0, stream>>>(E, r);

    // K4: out = (E @ vt^T) * r[row]  (bf16, M=2048 N=768 K=2048, z=8), batch-per-XCD
    gemm_mfma<4, false, 1><<<dim3(3, 8, 8), dim3(512), 0, stream>>>(
        E, vt, nullptr, r, out, nullptr,
        2048, 2048, 2048, 768,
        2048LL * 2048, 768LL * 2048, 2048LL * 768, 2048);
}